// Round 1
// baseline (457.030 us; speedup 1.0000x reference)
//
#include <hip/hip_runtime.h>

#define B_ 8
#define L_ 2048
#define D_ 512
#define BJ 64
#define NJB (L_ / BJ)  // 32

typedef __attribute__((ext_vector_type(4))) float  floatx4;
typedef __attribute__((ext_vector_type(8))) _Float16 halfx8;
typedef __attribute__((ext_vector_type(4))) int    intx4;

#define KSCALE 0.51012599f  // log2(e)/sqrt(8): exp2-domain softmax

static __device__ __forceinline__ unsigned short f2h_bits(float x) {
  _Float16 h = (_Float16)x;
  return __builtin_bit_cast(unsigned short, h);
}
static __device__ __forceinline__ float h2f(unsigned short b) {
  return (float)__builtin_bit_cast(_Float16, b);
}

typedef __attribute__((address_space(1))) const unsigned short gus;
typedef __attribute__((address_space(3))) unsigned short lus;
static __device__ __forceinline__ void gld_lds16(const unsigned short* g,
                                                 unsigned short* l) {
  __builtin_amdgcn_global_load_lds((gus*)g, (lus*)l, 16, 0, 0);
}

// ---------------------------------------------------------------------------
// prep: Kh[b][l][d] = in*kw (f16); Vt[b][d][l] = in*vw (f16, transposed);
//       Qh[b][l][d] = in*qw*KSCALE (f16, if ws fits).
// grid (L/64, D/64), 256 threads; batch loop inside -> weights read ONCE.
// ---------------------------------------------------------------------------
__global__ __launch_bounds__(256) void prep_kvq(const float* __restrict__ in,
                                                const float* __restrict__ qw,
                                                const float* __restrict__ kw,
                                                const float* __restrict__ vw,
                                                unsigned short* __restrict__ Kh,
                                                unsigned short* __restrict__ Vt,
                                                unsigned short* __restrict__ Qh,
                                                int has_qh) {
  const int lt = blockIdx.x * 64;
  const int dt = blockIdx.y * 64;
  const int t  = threadIdx.x;
  __shared__ unsigned short vtile[64][66];

  float4 qv[4], kv[4], vv[4];
  #pragma unroll
  for (int i = 0; i < 4; ++i) {
    int c  = i * 256 + t;
    int r  = c >> 4;
    int c4 = (c & 15) * 4;
    size_t wi_ = (size_t)(lt + r) * D_ + (dt + c4);
    qv[i] = *(const float4*)(qw + wi_);
    kv[i] = *(const float4*)(kw + wi_);
    vv[i] = *(const float4*)(vw + wi_);
  }
  for (int b = 0; b < B_; ++b) {
    #pragma unroll
    for (int i = 0; i < 4; ++i) {
      int c  = i * 256 + t;
      int r  = c >> 4;
      int c4 = (c & 15) * 4;
      size_t gi = ((size_t)b * L_ + (lt + r)) * D_ + (dt + c4);
      float4 iv = *(const float4*)(in + gi);
      uint2 pk;
      pk.x = (unsigned int)f2h_bits(iv.x * kv[i].x) |
             ((unsigned int)f2h_bits(iv.y * kv[i].y) << 16);
      pk.y = (unsigned int)f2h_bits(iv.z * kv[i].z) |
             ((unsigned int)f2h_bits(iv.w * kv[i].w) << 16);
      *(uint2*)(Kh + gi) = pk;
      if (has_qh) {
        uint2 pq;
        pq.x = (unsigned int)f2h_bits(iv.x * qv[i].x * KSCALE) |
               ((unsigned int)f2h_bits(iv.y * qv[i].y * KSCALE) << 16);
        pq.y = (unsigned int)f2h_bits(iv.z * qv[i].z * KSCALE) |
               ((unsigned int)f2h_bits(iv.w * qv[i].w * KSCALE) << 16);
        *(uint2*)(Qh + gi) = pq;
      }
      vtile[r][c4 + 0] = f2h_bits(iv.x * vv[i].x);
      vtile[r][c4 + 1] = f2h_bits(iv.y * vv[i].y);
      vtile[r][c4 + 2] = f2h_bits(iv.z * vv[i].z);
      vtile[r][c4 + 3] = f2h_bits(iv.w * vv[i].w);
    }
    __syncthreads();
    #pragma unroll
    for (int i = 0; i < 2; ++i) {
      int c  = i * 256 + t;
      int dd = c >> 3;
      int l8 = (c & 7) * 8;
      intx4 o;
      #pragma unroll
      for (int j = 0; j < 4; ++j)
        o[j] = (int)((unsigned int)vtile[l8 + 2 * j][dd] |
                     ((unsigned int)vtile[l8 + 2 * j + 1][dd] << 16));
      *(intx4*)(Vt + ((size_t)b * D_ + (dt + dd)) * L_ + (lt + l8)) = o;
    }
    __syncthreads();
  }
}

// ---------------------------------------------------------------------------
// flash: 8 waves = (wi 0..1: 32-row i-half) x (wj 0..3: 16-col j-strip for
// QK^T == 128-wide d-strip for PV). Q in regs (128 VGPR). K: swizzled LDS via
// global_load_lds prefetch. V: direct from L2 (XCD-pinned by batch). Cross-
// wave softmax: f16 max partials per jb; l partials merged in epilogue.
// grid: 256 blocks (b = bid&7 -> batch pinned per XCD), 512 threads.
// ---------------------------------------------------------------------------
__global__ __launch_bounds__(512) void flash8(const float* __restrict__ in,
                                              const float* __restrict__ qw,
                                              const unsigned short* __restrict__ Kh,
                                              const unsigned short* __restrict__ Vt,
                                              const unsigned short* __restrict__ Qh,
                                              float* __restrict__ out,
                                              int has_qh) {
  const int bid  = blockIdx.x;
  const int b    = bid & 7;            // batch == XCD (round-robin dispatch)
  const int i0   = (bid >> 3) * 64;
  const int tid  = threadIdx.x;
  const int w    = tid >> 6;
  const int lane = tid & 63;
  const int ln16 = lane & 15;
  const int quad = lane >> 4;
  const int wi   = w >> 2;             // i-half (32 rows)
  const int wj   = w & 3;              // j-strip (16 cols) / d-strip (128)

  __shared__ unsigned short Ksh[BJ][D_];   // 64 KB, linear rows, XOR-swizzled
  __shared__ unsigned short Psh[64][72];   // 9.2 KB (+8 pad)
  __shared__ unsigned short Mpart[64][4];  // f16 max partials, 512 B
  __shared__ float          Lpart[64][4];  // f32 sum partials, 1 KB

  // ---- Q fragments: rows i0 + wi*32 + it*16 + ln16, A-layout ----
  halfx8 qf[2][16];
  if (has_qh) {
    #pragma unroll
    for (int it = 0; it < 2; ++it) {
      const unsigned short* qp =
          Qh + ((size_t)b * L_ + (i0 + wi * 32 + it * 16 + ln16)) * D_;
      #pragma unroll
      for (int ks = 0; ks < 16; ++ks)
        qf[it][ks] = *(const halfx8*)(qp + ks * 32 + quad * 8);
    }
  } else {
    #pragma unroll
    for (int it = 0; it < 2; ++it) {
      const int qi = i0 + wi * 32 + it * 16 + ln16;
      const float* ip = in + ((size_t)b * L_ + qi) * D_;
      const float* wp = qw + (size_t)qi * D_;
      #pragma unroll
      for (int ks = 0; ks < 16; ++ks) {
        int d0 = ks * 32 + quad * 8;
        float4 a0 = *(const float4*)(ip + d0);
        float4 a1 = *(const float4*)(ip + d0 + 4);
        float4 w0 = *(const float4*)(wp + d0);
        float4 w1 = *(const float4*)(wp + d0 + 4);
        halfx8 q;
        q[0] = (_Float16)(a0.x * w0.x * KSCALE);
        q[1] = (_Float16)(a0.y * w0.y * KSCALE);
        q[2] = (_Float16)(a0.z * w0.z * KSCALE);
        q[3] = (_Float16)(a0.w * w0.w * KSCALE);
        q[4] = (_Float16)(a1.x * w1.x * KSCALE);
        q[5] = (_Float16)(a1.y * w1.y * KSCALE);
        q[6] = (_Float16)(a1.z * w1.z * KSCALE);
        q[7] = (_Float16)(a1.w * w1.w * KSCALE);
        qf[it][ks] = q;
      }
    }
  }

  float m_r[2][4], l_w[2][4];
  #pragma unroll
  for (int it = 0; it < 2; ++it)
    #pragma unroll
    for (int r = 0; r < 4; ++r) { m_r[it][r] = -1e30f; l_w[it][r] = 0.f; }
  floatx4 O[2][8];
  #pragma unroll
  for (int it = 0; it < 2; ++it)
    #pragma unroll
    for (int ct = 0; ct < 8; ++ct) O[it][ct] = (floatx4){0.f, 0.f, 0.f, 0.f};

  // ---- prologue: DMA K tile 0 (pre-swizzled source -> linear LDS) ----
  {
    const unsigned short* kb = Kh + ((size_t)b * L_ + w * 8) * D_;
    #pragma unroll
    for (int k = 0; k < 8; ++k) {
      int r = w * 8 + k;
      gld_lds16(kb + (size_t)k * D_ + ((lane ^ (r & 7)) << 3), &Ksh[r][0]);
    }
  }
  __syncthreads();

  for (int jb = 0; jb < NJB; ++jb) {
    const int j0 = jb * BJ;

    // ---- S = Q K^T for this wave's 16 j-columns (swizzled Ksh reads) ----
    floatx4 s[2];
    s[0] = (floatx4){0.f, 0.f, 0.f, 0.f};
    s[1] = (floatx4){0.f, 0.f, 0.f, 0.f};
    const unsigned short* krp = &Ksh[wj * 16 + ln16][0];
    #pragma unroll
    for (int ks = 0; ks < 16; ++ks) {
      int cc = ((ks * 4 + quad) ^ (ln16 & 7)) << 3;
      halfx8 bk = *(const halfx8*)(krp + cc);
      s[0] = __builtin_amdgcn_mfma_f32_16x16x32_f16(qf[0][ks], bk, s[0], 0, 0, 0);
      s[1] = __builtin_amdgcn_mfma_f32_16x16x32_f16(qf[1][ks], bk, s[1], 0, 0, 0);
    }

    // ---- local (16-j) row max -> f16 partials ----
    float mloc[2][4];
    #pragma unroll
    for (int it = 0; it < 2; ++it)
      #pragma unroll
      for (int r = 0; r < 4; ++r) {
        float m = s[it][r];
        #pragma unroll
        for (int off = 1; off < 16; off <<= 1) m = fmaxf(m, __shfl_xor(m, off));
        mloc[it][r] = m;
      }
    if (ln16 == 0) {
      #pragma unroll
      for (int it = 0; it < 2; ++it)
        #pragma unroll
        for (int r = 0; r < 4; ++r)
          Mpart[wi * 32 + it * 16 + quad * 4 + r][wj] = f2h_bits(mloc[it][r]);
    }
    __syncthreads();  // bar1: Mpart ready; Ksh consumed; prev Psh reads done

    // ---- combine max, P = exp2(S-m), per-wave l partial, rescale O ----
    float al[2][4];
    bool upd = false;
    #pragma unroll
    for (int it = 0; it < 2; ++it)
      #pragma unroll
      for (int r = 0; r < 4; ++r) {
        int row = wi * 32 + it * 16 + quad * 4 + r;
        uint2 mp = *(const uint2*)(&Mpart[row][0]);
        float mt = fmaxf(fmaxf(h2f((unsigned short)(mp.x & 0xffff)),
                               h2f((unsigned short)(mp.x >> 16))),
                         fmaxf(h2f((unsigned short)(mp.y & 0xffff)),
                               h2f((unsigned short)(mp.y >> 16))));
        float mn = fmaxf(m_r[it][r], mt);
        al[it][r] = exp2f(m_r[it][r] - mn);
        upd = upd || (mn != m_r[it][r]);
        m_r[it][r] = mn;
      }
    #pragma unroll
    for (int it = 0; it < 2; ++it)
      #pragma unroll
      for (int r = 0; r < 4; ++r) {
        int row = wi * 32 + it * 16 + quad * 4 + r;
        float p = exp2f(s[it][r] - m_r[it][r]);
        Psh[row][wj * 16 + ln16] = f2h_bits(p);
        float ls = p;
        #pragma unroll
        for (int off = 1; off < 16; off <<= 1) ls += __shfl_xor(ls, off);
        l_w[it][r] = l_w[it][r] * al[it][r] + ls;
      }
    if (__any((int)upd)) {
      #pragma unroll
      for (int it = 0; it < 2; ++it)
        #pragma unroll
        for (int ct = 0; ct < 8; ++ct)
          #pragma unroll
          for (int r = 0; r < 4; ++r) O[it][ct][r] *= al[it][r];
    }
    __syncthreads();  // bar2: Psh ready (DMA not yet issued -> no drain cost)

    // ---- prefetch K tile jb+1 (overlaps PV; drained at bar3) ----
    if (jb + 1 < NJB) {
      const unsigned short* kb =
          Kh + ((size_t)b * L_ + j0 + BJ + w * 8) * D_;
      #pragma unroll
      for (int k = 0; k < 8; ++k) {
        int r = w * 8 + k;
        gld_lds16(kb + (size_t)k * D_ + ((lane ^ (r & 7)) << 3), &Ksh[r][0]);
      }
    }

    // ---- O += P V for this wave's 128-wide d-strip (V direct from L2) ----
    const unsigned short* vb0 =
        Vt + ((size_t)b * D_ + wj * 128) * L_ + j0 + quad * 8;
    #pragma unroll
    for (int kc = 0; kc < 2; ++kc) {
      halfx8 pf0 = *(const halfx8*)(&Psh[wi * 32 + ln16][kc * 32 + quad * 8]);
      halfx8 pf1 = *(const halfx8*)(&Psh[wi * 32 + 16 + ln16][kc * 32 + quad * 8]);
      const unsigned short* vb = vb0 + kc * 32;
      #pragma unroll
      for (int ct = 0; ct < 8; ++ct) {
        halfx8 vf = *(const halfx8*)(vb + (size_t)(ct * 16 + ln16) * L_);
        O[0][ct] = __builtin_amdgcn_mfma_f32_16x16x32_f16(pf0, vf, O[0][ct], 0, 0, 0);
        O[1][ct] = __builtin_amdgcn_mfma_f32_16x16x32_f16(pf1, vf, O[1][ct], 0, 0, 0);
      }
    }
    __syncthreads();  // bar3: vmcnt(0) drain -> Ksh[jb+1] landed; Psh free
  }

  // ---- epilogue: merge l partials, divide, store ----
  if (ln16 == 0) {
    #pragma unroll
    for (int it = 0; it < 2; ++it)
      #pragma unroll
      for (int r = 0; r < 4; ++r)
        Lpart[wi * 32 + it * 16 + quad * 4 + r][wj] = l_w[it][r];
  }
  __syncthreads();
  float inv[2][4];
  #pragma unroll
  for (int it = 0; it < 2; ++it)
    #pragma unroll
    for (int r = 0; r < 4; ++r) {
      int row = wi * 32 + it * 16 + quad * 4 + r;
      float4 lp = *(const float4*)(&Lpart[row][0]);
      inv[it][r] = 1.0f / (lp.x + lp.y + lp.z + lp.w);
    }
  #pragma unroll
  for (int it = 0; it < 2; ++it) {
    float* op = out + ((size_t)b * L_ + i0 + wi * 32 + it * 16 + quad * 4) * D_ +
                wj * 128 + ln16;
    #pragma unroll
    for (int r = 0; r < 4; ++r)
      #pragma unroll
      for (int ct = 0; ct < 8; ++ct)
        op[(size_t)r * D_ + ct * 16] = O[it][ct][r] * inv[it][r];
  }
}

// ---------------------------------------------------------------------------
extern "C" void kernel_launch(void* const* d_in, const int* in_sizes, int n_in,
                              void* d_out, int out_size, void* d_ws, size_t ws_size,
                              hipStream_t stream) {
  const float* in = (const float*)d_in[0];
  const float* qw = (const float*)d_in[1];
  const float* kw = (const float*)d_in[2];
  const float* vw = (const float*)d_in[3];
  float* out = (float*)d_out;

  const size_t seg = (size_t)B_ * L_ * D_;          // elements per f16 tensor
  unsigned short* Kh = (unsigned short*)d_ws;       // 16.78 MB
  unsigned short* Vt = Kh + seg;                    // 16.78 MB
  unsigned short* Qh = Vt + seg;                    // 16.78 MB (optional)
  const int has_qh = (ws_size >= 3 * seg * sizeof(unsigned short)) ? 1 : 0;

  dim3 gp(L_ / 64, D_ / 64);
  prep_kvq<<<gp, dim3(256), 0, stream>>>(in, qw, kw, vw, Kh, Vt, Qh, has_qh);
  flash8<<<dim3(256), dim3(512), 0, stream>>>(in, qw, Kh, Vt, Qh, out, has_qh);
}